// Round 3
// baseline (607.004 us; speedup 1.0000x reference)
//
#include <hip/hip_runtime.h>
#include <hip/hip_bf16.h>

// ---------------------------------------------------------------------------
// K0: transpose six [256x256] fp32 weight matrices [o][c] -> fp32 [c][o]
// ---------------------------------------------------------------------------
__global__ __launch_bounds__(256) void k_wt(const float* __restrict__ w0,
                                            const float* __restrict__ w1,
                                            const float* __restrict__ w2,
                                            const float* __restrict__ w3,
                                            const float* __restrict__ w4,
                                            const float* __restrict__ w5,
                                            float* __restrict__ wt) {
  int bx = blockIdx.x;
  int mat = bx >> 8;
  int o = bx & 255;
  int c = threadIdx.x;
  const float* p = mat == 0 ? w0 : mat == 1 ? w1 : mat == 2 ? w2
                 : mat == 3 ? w3 : mat == 4 ? w4 : w5;
  wt[(size_t)mat * 65536 + (size_t)c * 256 + o] = p[o * 256 + c];
}

// ---------------------------------------------------------------------------
// K1: fused 5x depthwise 3x3 conv per (b,c) plane + pooled means.
// convV:   [b][c][h*64+w]        (A^T layout for the v GEMM, mblk=4096)
// qhm/khm: [b][c][h]  (row mean) (A^T layout, mblk=64)
// qwm/kwm: [b][c][w]  (col mean)
// ---------------------------------------------------------------------------
__global__ __launch_bounds__(256) void k_conv(
    const float* __restrict__ x,
    const float* __restrict__ wqh, const float* __restrict__ bqh,
    const float* __restrict__ wkh, const float* __restrict__ bkh,
    const float* __restrict__ wv,  const float* __restrict__ bv,
    const float* __restrict__ wqw, const float* __restrict__ bqw,
    const float* __restrict__ wkw, const float* __restrict__ bkw,
    float* __restrict__ convV,
    float* __restrict__ qhm, float* __restrict__ khm,
    float* __restrict__ qwm, float* __restrict__ kwm) {
  __shared__ float xs[66 * 66];
  __shared__ float wl[5][9];
  __shared__ float bl[5];
  __shared__ float red[4][64];

  int bx = blockIdx.x;
  int b = bx >> 8;
  int c = bx & 255;
  int tid = threadIdx.x;

  const float* xp = x + (size_t)(b * 256 + c) * 4096;
  for (int idx = tid; idx < 66 * 66; idx += 256) {
    int gy = idx / 66, gx = idx % 66;
    int sy = gy - 1, sx = gx - 1;
    float v = 0.f;
    if (sy >= 0 && sy < 64 && sx >= 0 && sx < 64) v = xp[sy * 64 + sx];
    xs[idx] = v;
  }
  if (tid < 45) {
    int cw = tid / 9, wi = tid % 9;
    const float* wp = cw == 0 ? wqh : cw == 1 ? wkh : cw == 2 ? wv
                    : cw == 3 ? wqw : wkw;
    wl[cw][wi] = wp[c * 9 + wi];
  } else if (tid < 50) {
    int cw = tid - 45;
    const float* bp = cw == 0 ? bqh : cw == 1 ? bkh : cw == 2 ? bv
                    : cw == 3 ? bqw : bkw;
    bl[cw] = bp[c];
  }
  __syncthreads();

  int w = tid & 63;
  int wave = tid >> 6;
  float csqw = 0.f, cskw = 0.f;

  for (int i = 0; i < 16; i++) {
    int h = wave * 16 + i;
    float a0 = 0.f, a1 = 0.f, a2 = 0.f, a3 = 0.f, a4 = 0.f;
#pragma unroll
    for (int ky = 0; ky < 3; ky++)
#pragma unroll
      for (int kx = 0; kx < 3; kx++) {
        float xv = xs[(h + ky) * 66 + (w + kx)];
        int wi = ky * 3 + kx;
        a0 += xv * wl[0][wi];
        a1 += xv * wl[1][wi];
        a2 += xv * wl[2][wi];
        a3 += xv * wl[3][wi];
        a4 += xv * wl[4][wi];
      }
    convV[(size_t)(b * 256 + c) * 4096 + h * 64 + w] = a2 + bl[2];
    float r0 = a0, r1 = a1;
#pragma unroll
    for (int off = 32; off > 0; off >>= 1) {
      r0 += __shfl_down(r0, off, 64);
      r1 += __shfl_down(r1, off, 64);
    }
    if (w == 0) {
      qhm[(size_t)(b * 256 + c) * 64 + h] = r0 * (1.f / 64.f) + bl[0];
      khm[(size_t)(b * 256 + c) * 64 + h] = r1 * (1.f / 64.f) + bl[1];
    }
    csqw += a3;
    cskw += a4;
  }

  red[wave][w] = csqw;
  __syncthreads();
  if (tid < 64) {
    float s = red[0][tid] + red[1][tid] + red[2][tid] + red[3][tid];
    qwm[(size_t)(b * 256 + c) * 64 + tid] = s * (1.f / 64.f) + bl[3];
  }
  __syncthreads();
  red[wave][w] = cskw;
  __syncthreads();
  if (tid < 64) {
    float s = red[0][tid] + red[1][tid] + red[2][tid] + red[3][tid];
    kwm[(size_t)(b * 256 + c) * 64 + tid] = s * (1.f / 64.f) + bl[4];
  }
}

// ---------------------------------------------------------------------------
// Generic GEMM: C[m][n] = sum_k At[b][k][m-inner] * Wt[k][n] + bias[n]
// At is batched k-major: addr = (m0/mblk)*256*mblk + k*mblk + (m0%mblk) + dm
// N = K = 256. Tile 64x64, 256 threads, 4x4 per thread.
// ---------------------------------------------------------------------------
__global__ __launch_bounds__(256) void k_gemm(const float* __restrict__ At,
                                              const float* __restrict__ Wt,
                                              const float* __restrict__ bias,
                                              float* __restrict__ Cout,
                                              int mblk) {
  __shared__ __align__(16) float As[32 * 64];
  __shared__ __align__(16) float Ws[32 * 64];

  int m0 = blockIdx.x * 64;
  int n0 = blockIdx.y * 64;
  int tid = threadIdx.x;
  int batch = m0 / mblk;
  int inner = m0 % mblk;
  const float* Ab = At + (size_t)batch * 256 * mblk + inner;

  int tx = tid & 15, ty = tid >> 4;
  int lk = tid >> 6;   // 0..3
  int lm = tid & 63;   // 0..63
  float acc[4][4] = {};

  for (int kc = 0; kc < 256; kc += 32) {
    __syncthreads();
#pragma unroll
    for (int r = 0; r < 8; r++) {
      int kk = lk + r * 4;
      As[kk * 64 + lm] = Ab[(size_t)(kc + kk) * mblk + lm];
      Ws[kk * 64 + lm] = Wt[(kc + kk) * 256 + n0 + lm];
    }
    __syncthreads();
#pragma unroll
    for (int kk = 0; kk < 32; kk++) {
      float4 av = *(const float4*)&As[kk * 64 + ty * 4];
      float4 wv = *(const float4*)&Ws[kk * 64 + tx * 4];
      float a_[4] = {av.x, av.y, av.z, av.w};
      float w_[4] = {wv.x, wv.y, wv.z, wv.w};
#pragma unroll
      for (int ii = 0; ii < 4; ii++)
#pragma unroll
        for (int jj = 0; jj < 4; jj++) acc[ii][jj] += a_[ii] * w_[jj];
    }
  }

#pragma unroll
  for (int ii = 0; ii < 4; ii++) {
    int m = m0 + ty * 4 + ii;
#pragma unroll
    for (int jj = 0; jj < 4; jj++) {
      int n = n0 + tx * 4 + jj;
      Cout[(size_t)m * 256 + n] = acc[ii][jj] + bias[n];
    }
  }
}

// ---------------------------------------------------------------------------
// K3: attention row softmax. One wave per (b, head, i).
// q,k: [b*64+s][256] (head hd occupies cols hd*32..+31)
// attn[b][hd][i][j] = softmax_j(scale * q.k + Bias[hd][i][j])
// ---------------------------------------------------------------------------
__global__ __launch_bounds__(64) void k_attn(const float* __restrict__ q,
                                             const float* __restrict__ k,
                                             const float* __restrict__ Bbias,
                                             float* __restrict__ attn,
                                             float scale) {
  int bx = blockIdx.x;
  int i = bx & 63, hd = (bx >> 6) & 7, b = bx >> 9;
  int j = threadIdx.x;
  __shared__ float qs[32];
  if (j < 32) qs[j] = q[(size_t)(b * 64 + i) * 256 + hd * 32 + j];
  __syncthreads();
  const float* kp = k + (size_t)(b * 64 + j) * 256 + hd * 32;
  float dot = 0.f;
#pragma unroll
  for (int d = 0; d < 32; d++) dot += qs[d] * kp[d];
  float logit = dot * scale + Bbias[(hd * 64 + i) * 64 + j];
  float mx = logit;
#pragma unroll
  for (int off = 32; off > 0; off >>= 1)
    mx = fmaxf(mx, __shfl_xor(mx, off, 64));
  float e = __expf(logit - mx);
  float sum = e;
#pragma unroll
  for (int off = 32; off > 0; off >>= 1) sum += __shfl_xor(sum, off, 64);
  attn[(size_t)((b * 8 + hd) * 64 + i) * 64 + j] = e / sum;
}

// ---------------------------------------------------------------------------
// K5a: r1[b][hd][h][w*32+dv] = sum_j attn_h[b][hd][h][j] * vlin[b][j*64+w][hd*32+dv]
// One block per (b, hd, 64-col chunk). 64x64 tile, K=64.
// ---------------------------------------------------------------------------
__global__ __launch_bounds__(256) void k_av(const float* __restrict__ attn,
                                            const float* __restrict__ vlin,
                                            float* __restrict__ r1) {
  __shared__ __align__(16) float As[64 * 65];  // As[j][i] = attn[i][j]
  __shared__ __align__(16) float Bs[64 * 64];  // Bs[j][col]

  int bx = blockIdx.x;
  int cc = bx & 31, hd = (bx >> 5) & 7, b = bx >> 8;
  int tid = threadIdx.x;
  int l = tid & 63, g = tid >> 6;

  const float* ap = attn + (size_t)(b * 8 + hd) * 4096;
#pragma unroll
  for (int r = 0; r < 16; r++) {
    int i = g + r * 4;
    As[l * 65 + i] = ap[i * 64 + l];
  }
  int colg0 = cc * 64;
#pragma unroll
  for (int r = 0; r < 16; r++) {
    int j = g + r * 4;
    int colg = colg0 + l;
    int w = colg >> 5, dv = colg & 31;
    Bs[j * 64 + l] = vlin[(size_t)(b * 4096 + j * 64 + w) * 256 + hd * 32 + dv];
  }
  __syncthreads();

  int tx = tid & 15, ty = tid >> 4;
  float acc[4][4] = {};
  for (int j = 0; j < 64; j++) {
    float4 bv = *(const float4*)&Bs[j * 64 + tx * 4];
    float b_[4] = {bv.x, bv.y, bv.z, bv.w};
    float a_[4];
#pragma unroll
    for (int ii = 0; ii < 4; ii++) a_[ii] = As[j * 65 + ty * 4 + ii];
#pragma unroll
    for (int ii = 0; ii < 4; ii++)
#pragma unroll
      for (int jj = 0; jj < 4; jj++) acc[ii][jj] += a_[ii] * b_[jj];
  }

  float* rp = r1 + (size_t)(b * 8 + hd) * 64 * 2048;
#pragma unroll
  for (int ii = 0; ii < 4; ii++) {
    int row = ty * 4 + ii;
    float4 v = make_float4(acc[ii][0], acc[ii][1], acc[ii][2], acc[ii][3]);
    *(float4*)&rp[(size_t)row * 2048 + colg0 + tx * 4] = v;
  }
}

// ---------------------------------------------------------------------------
// K5b: y_T[(b*256 + hd*32 + dv)][h*64 + w'] = sum_w r1[b][hd][h][w*32+dv] * attn_w[b][hd][w][w']
// One block per (b, hd, h). Output in A^T layout for fc_o (mblk=4096).
// ---------------------------------------------------------------------------
__global__ __launch_bounds__(256) void k_rw(const float* __restrict__ r1,
                                            const float* __restrict__ attnw,
                                            float* __restrict__ yT) {
  __shared__ __align__(16) float rr[2048];
  __shared__ __align__(16) float aw[4096];

  int bx = blockIdx.x;
  int h = bx & 63, hd = (bx >> 6) & 7, b = bx >> 9;
  int tid = threadIdx.x;

  const float* rp = r1 + (size_t)((b * 8 + hd) * 64 + h) * 2048;
#pragma unroll
  for (int r = 0; r < 8; r++) rr[tid + r * 256] = rp[tid + r * 256];
  const float* ap = attnw + (size_t)(b * 8 + hd) * 4096;
#pragma unroll
  for (int r = 0; r < 16; r++) aw[tid + r * 256] = ap[tid + r * 256];
  __syncthreads();

  int wp = tid & 63;
  int dv0 = (tid >> 6) * 8;
  float acc[8] = {};
  for (int w = 0; w < 64; w++) {
    float a = aw[w * 64 + wp];
    float4 r4a = *(const float4*)&rr[w * 32 + dv0];
    float4 r4b = *(const float4*)&rr[w * 32 + dv0 + 4];
    float rv[8] = {r4a.x, r4a.y, r4a.z, r4a.w, r4b.x, r4b.y, r4b.z, r4b.w};
#pragma unroll
    for (int d = 0; d < 8; d++) acc[d] += a * rv[d];
  }

  float* yp = yT + (size_t)b * 256 * 4096 + (size_t)(hd * 32) * 4096 + h * 64 + wp;
#pragma unroll
  for (int d = 0; d < 8; d++) yp[(size_t)(dv0 + d) * 4096] = acc[d];
}

// ---------------------------------------------------------------------------
extern "C" void kernel_launch(void* const* d_in, const int* in_sizes, int n_in,
                              void* d_out, int out_size, void* d_ws,
                              size_t ws_size, hipStream_t stream) {
  const float* x      = (const float*)d_in[0];
  const float* dwqh_w = (const float*)d_in[1];
  const float* dwqh_b = (const float*)d_in[2];
  const float* fcqh_w = (const float*)d_in[3];
  const float* fcqh_b = (const float*)d_in[4];
  const float* dwkh_w = (const float*)d_in[5];
  const float* dwkh_b = (const float*)d_in[6];
  const float* fckh_w = (const float*)d_in[7];
  const float* fckh_b = (const float*)d_in[8];
  const float* Bh     = (const float*)d_in[9];
  const float* dwv_w  = (const float*)d_in[10];
  const float* dwv_b  = (const float*)d_in[11];
  const float* fcv_w  = (const float*)d_in[12];
  const float* fcv_b  = (const float*)d_in[13];
  const float* dwqw_w = (const float*)d_in[14];
  const float* dwqw_b = (const float*)d_in[15];
  const float* fcqw_w = (const float*)d_in[16];
  const float* fcqw_b = (const float*)d_in[17];
  const float* dwkw_w = (const float*)d_in[18];
  const float* dwkw_b = (const float*)d_in[19];
  const float* fckw_w = (const float*)d_in[20];
  const float* fckw_b = (const float*)d_in[21];
  const float* Bw     = (const float*)d_in[22];
  const float* fco_w  = (const float*)d_in[23];
  const float* fco_b  = (const float*)d_in[24];

  float* ws = (float*)d_ws;
  float* bufA = ws;                  // 16777216 floats: convV, then r1
  float* bufB = ws + 16777216;       // 16777216 floats: vlin, then yT
  float* wt   = ws + 33554432;       // 6 * 65536
  float* qhm  = ws + 33947648;       // 262144 each
  float* khm  = ws + 34209792;
  float* qwm  = ws + 34471936;
  float* kwm  = ws + 34734080;
  float* qhl  = ws + 34996224;
  float* khl  = ws + 35258368;
  float* qwl  = ws + 35520512;
  float* kwl  = ws + 35782656;
  float* ah   = ws + 36044800;       // 524288
  float* awt  = ws + 36569088;       // 524288
  if (ws_size < 37093376ull * 4ull) return;  // workspace too small -> visible fail

  const float scale = 0.17677669529663687f;  // 32^-0.5

  k_wt<<<1536, 256, 0, stream>>>(fcqh_w, fckh_w, fcv_w, fcqw_w, fckw_w, fco_w, wt);
  k_conv<<<4096, 256, 0, stream>>>(x, dwqh_w, dwqh_b, dwkh_w, dwkh_b, dwv_w,
                                   dwv_b, dwqw_w, dwqw_b, dwkw_w, dwkw_b, bufA,
                                   qhm, khm, qwm, kwm);
  k_gemm<<<dim3(16, 4), 256, 0, stream>>>(qhm, wt + 0 * 65536, fcqh_b, qhl, 64);
  k_gemm<<<dim3(16, 4), 256, 0, stream>>>(khm, wt + 1 * 65536, fckh_b, khl, 64);
  k_gemm<<<dim3(16, 4), 256, 0, stream>>>(qwm, wt + 3 * 65536, fcqw_b, qwl, 64);
  k_gemm<<<dim3(16, 4), 256, 0, stream>>>(kwm, wt + 4 * 65536, fckw_b, kwl, 64);
  k_attn<<<8192, 64, 0, stream>>>(qhl, khl, Bh, ah, scale);
  k_attn<<<8192, 64, 0, stream>>>(qwl, kwl, Bw, awt, scale);
  k_gemm<<<dim3(1024, 4), 256, 0, stream>>>(bufA, wt + 2 * 65536, fcv_b, bufB, 4096);
  k_av<<<4096, 256, 0, stream>>>(ah, bufB, bufA);
  k_rw<<<8192, 256, 0, stream>>>(bufA, awt, bufB);
  k_gemm<<<dim3(1024, 4), 256, 0, stream>>>(bufB, wt + 5 * 65536, fco_b,
                                            (float*)d_out, 4096);
}

// Round 4
// 435.324 us; speedup vs baseline: 1.3944x; 1.3944x over previous
//
#include <hip/hip_runtime.h>
#include <hip/hip_bf16.h>

typedef float f4v __attribute__((ext_vector_type(4)));
typedef short s8v __attribute__((ext_vector_type(8)));

__device__ __forceinline__ float bf2f(ushort u) {
  union { ushort s; __hip_bfloat16 h; } c; c.s = u;
  return __bfloat162float(c.h);
}
__device__ __forceinline__ ushort f2bf(float f) {
  union { ushort s; __hip_bfloat16 h; } c; c.h = __float2bfloat16(f);
  return c.s;
}

// ---------------------------------------------------------------------------
// K0: transpose four [256x256] fp32 weight matrices [o][c] -> fp32 [c][o]
// (for the small pooled GEMMs)
// ---------------------------------------------------------------------------
__global__ __launch_bounds__(256) void k_wt(const float* __restrict__ w0,
                                            const float* __restrict__ w1,
                                            const float* __restrict__ w2,
                                            const float* __restrict__ w3,
                                            float* __restrict__ wt) {
  int bx = blockIdx.x;
  int mat = bx >> 8;
  int o = bx & 255;
  int c = threadIdx.x;
  const float* p = mat == 0 ? w0 : mat == 1 ? w1 : mat == 2 ? w2 : w3;
  wt[(size_t)mat * 65536 + (size_t)c * 256 + o] = p[o * 256 + c];
}

// ---------------------------------------------------------------------------
// K0b: cast fc_v / fc_o weights to bf16, KEEPING [n][k] layout (k-contig).
// ---------------------------------------------------------------------------
__global__ __launch_bounds__(256) void k_cvt(const float* __restrict__ wv,
                                             const float* __restrict__ wo,
                                             ushort* __restrict__ wbf) {
  int idx = blockIdx.x * 256 + threadIdx.x;
  const float* src = (idx >> 16) ? wo : wv;
  wbf[idx] = f2bf(src[idx & 65535]);
}

// ---------------------------------------------------------------------------
// K1: fused 5x depthwise 3x3 conv per (b,c) plane + pooled means.
// convV (bf16): [b][c][pix]   (k-major; transposed by k_tr for the v GEMM)
// qhm/khm/qwm/kwm (fp32): [b][c][64] (A^T layout for small GEMMs, mblk=64)
// ---------------------------------------------------------------------------
__global__ __launch_bounds__(256) void k_conv(
    const float* __restrict__ x,
    const float* __restrict__ wqh, const float* __restrict__ bqh,
    const float* __restrict__ wkh, const float* __restrict__ bkh,
    const float* __restrict__ wv,  const float* __restrict__ bv,
    const float* __restrict__ wqw, const float* __restrict__ bqw,
    const float* __restrict__ wkw, const float* __restrict__ bkw,
    ushort* __restrict__ convV,
    float* __restrict__ qhm, float* __restrict__ khm,
    float* __restrict__ qwm, float* __restrict__ kwm) {
  __shared__ float xs[66 * 66];
  __shared__ float wl[5][9];
  __shared__ float bl[5];
  __shared__ float red[4][64];

  int bx = blockIdx.x;
  int b = bx >> 8;
  int c = bx & 255;
  int tid = threadIdx.x;

  const float* xp = x + (size_t)(b * 256 + c) * 4096;
  for (int idx = tid; idx < 66 * 66; idx += 256) {
    int gy = idx / 66, gx = idx % 66;
    int sy = gy - 1, sx = gx - 1;
    float v = 0.f;
    if (sy >= 0 && sy < 64 && sx >= 0 && sx < 64) v = xp[sy * 64 + sx];
    xs[idx] = v;
  }
  if (tid < 45) {
    int cw = tid / 9, wi = tid % 9;
    const float* wp = cw == 0 ? wqh : cw == 1 ? wkh : cw == 2 ? wv
                    : cw == 3 ? wqw : wkw;
    wl[cw][wi] = wp[c * 9 + wi];
  } else if (tid < 50) {
    int cw = tid - 45;
    const float* bp = cw == 0 ? bqh : cw == 1 ? bkh : cw == 2 ? bv
                    : cw == 3 ? bqw : bkw;
    bl[cw] = bp[c];
  }
  __syncthreads();

  int w = tid & 63;
  int wave = tid >> 6;
  float csqw = 0.f, cskw = 0.f;

  for (int i = 0; i < 16; i++) {
    int h = wave * 16 + i;
    float a0 = 0.f, a1 = 0.f, a2 = 0.f, a3 = 0.f, a4 = 0.f;
#pragma unroll
    for (int ky = 0; ky < 3; ky++)
#pragma unroll
      for (int kx = 0; kx < 3; kx++) {
        float xv = xs[(h + ky) * 66 + (w + kx)];
        int wi = ky * 3 + kx;
        a0 += xv * wl[0][wi];
        a1 += xv * wl[1][wi];
        a2 += xv * wl[2][wi];
        a3 += xv * wl[3][wi];
        a4 += xv * wl[4][wi];
      }
    convV[(size_t)(b * 256 + c) * 4096 + h * 64 + w] = f2bf(a2 + bl[2]);
    float r0 = a0, r1 = a1;
#pragma unroll
    for (int off = 32; off > 0; off >>= 1) {
      r0 += __shfl_down(r0, off, 64);
      r1 += __shfl_down(r1, off, 64);
    }
    if (w == 0) {
      qhm[(size_t)(b * 256 + c) * 64 + h] = r0 * (1.f / 64.f) + bl[0];
      khm[(size_t)(b * 256 + c) * 64 + h] = r1 * (1.f / 64.f) + bl[1];
    }
    csqw += a3;
    cskw += a4;
  }

  red[wave][w] = csqw;
  __syncthreads();
  if (tid < 64) {
    float s = red[0][tid] + red[1][tid] + red[2][tid] + red[3][tid];
    qwm[(size_t)(b * 256 + c) * 64 + tid] = s * (1.f / 64.f) + bl[3];
  }
  __syncthreads();
  red[wave][w] = cskw;
  __syncthreads();
  if (tid < 64) {
    float s = red[0][tid] + red[1][tid] + red[2][tid] + red[3][tid];
    kwm[(size_t)(b * 256 + c) * 64 + tid] = s * (1.f / 64.f) + bl[4];
  }
}

// ---------------------------------------------------------------------------
// K1b: transpose convV [b][c][pix] bf16 -> convA [b*4096+pix][c] bf16
// 64x64 tiles through LDS; both global sides coalesced.
// ---------------------------------------------------------------------------
__global__ __launch_bounds__(256) void k_tr(const ushort* __restrict__ convV,
                                            ushort* __restrict__ convA) {
  __shared__ ushort ls[64 * 68];
  int bx = blockIdx.x;
  int pt = bx & 63, ct = (bx >> 6) & 3, b = bx >> 8;
  int p0 = pt * 64, c0 = ct * 64;
  int tid = threadIdx.x;
  int lane = tid & 63, grp = tid >> 6;

#pragma unroll
  for (int r = 0; r < 16; r++) {
    int c = grp * 16 + r;
    ls[lane * 68 + c] = convV[(size_t)(b * 256 + c0 + c) * 4096 + p0 + lane];
  }
  __syncthreads();
#pragma unroll
  for (int r = 0; r < 16; r++) {
    int pix = grp * 16 + r;
    convA[(size_t)(b * 4096 + p0 + pix) * 256 + c0 + lane] = ls[pix * 68 + lane];
  }
}

// ---------------------------------------------------------------------------
// K2: bf16 MFMA GEMM. out[m][n] = sum_k A[m][k] * W[n][k] + bias[n]
// A: [M][256] bf16 row-major (k contiguous). W: [256][256] bf16 (torch layout,
// k contiguous). 128x128 tile, 4 waves (2x2 of 64x64), 4x4 mfma_16x16x32_bf16
// per wave. LDS rows padded 32->40 bf16 to kill ds_read_b128 bank conflicts.
// ---------------------------------------------------------------------------
template <int OUT_BF16>
__global__ __launch_bounds__(256) void k_mm(const ushort* __restrict__ A,
                                            const ushort* __restrict__ W,
                                            const float* __restrict__ bias,
                                            void* __restrict__ out) {
  __shared__ __align__(16) ushort As[128 * 40];
  __shared__ __align__(16) ushort Bs[128 * 40];

  int m0 = blockIdx.x * 128;
  int n0 = blockIdx.y * 128;
  int tid = threadIdx.x;
  int lane = tid & 63, wave = tid >> 6;
  int wm = (wave & 1) * 64, wn = (wave >> 1) * 64;
  int tm = lane & 15, quad = lane >> 4;

  f4v acc[4][4] = {};

  for (int kc = 0; kc < 256; kc += 32) {
    __syncthreads();
#pragma unroll
    for (int h = 0; h < 2; h++) {
      int ch = tid + h * 256;           // 0..511
      int mr = ch >> 2, k8 = (ch & 3) * 8;
      *(float4*)&As[mr * 40 + k8] =
          *(const float4*)&A[(size_t)(m0 + mr) * 256 + kc + k8];
      *(float4*)&Bs[mr * 40 + k8] =
          *(const float4*)&W[(size_t)(n0 + mr) * 256 + kc + k8];
    }
    __syncthreads();

    s8v a[4], b[4];
#pragma unroll
    for (int mi = 0; mi < 4; mi++)
      a[mi] = *(const s8v*)&As[(wm + mi * 16 + tm) * 40 + quad * 8];
#pragma unroll
    for (int ni = 0; ni < 4; ni++)
      b[ni] = *(const s8v*)&Bs[(wn + ni * 16 + tm) * 40 + quad * 8];
#pragma unroll
    for (int mi = 0; mi < 4; mi++)
#pragma unroll
      for (int ni = 0; ni < 4; ni++)
        acc[mi][ni] = __builtin_amdgcn_mfma_f32_16x16x32_bf16(
            a[mi], b[ni], acc[mi][ni], 0, 0, 0);
  }

  // C/D layout: col = lane&15, row = quad*4 + reg  [verified m89/m91]
#pragma unroll
  for (int mi = 0; mi < 4; mi++) {
#pragma unroll
    for (int ni = 0; ni < 4; ni++) {
      int col = n0 + wn + ni * 16 + tm;
      float bv = bias[col];
#pragma unroll
      for (int r = 0; r < 4; r++) {
        int row = m0 + wm + mi * 16 + quad * 4 + r;
        float v = acc[mi][ni][r] + bv;
        if (OUT_BF16)
          ((ushort*)out)[(size_t)row * 256 + col] = f2bf(v);
        else
          ((float*)out)[(size_t)row * 256 + col] = v;
      }
    }
  }
}

// ---------------------------------------------------------------------------
// Small fp32 GEMM for pooled q/k linears (M=1024): C = At^T * Wt + bias
// ---------------------------------------------------------------------------
__global__ __launch_bounds__(256) void k_gemm(const float* __restrict__ At,
                                              const float* __restrict__ Wt,
                                              const float* __restrict__ bias,
                                              float* __restrict__ Cout,
                                              int mblk) {
  __shared__ __align__(16) float As[32 * 64];
  __shared__ __align__(16) float Ws[32 * 64];

  int m0 = blockIdx.x * 64;
  int n0 = blockIdx.y * 64;
  int tid = threadIdx.x;
  int batch = m0 / mblk;
  int inner = m0 % mblk;
  const float* Ab = At + (size_t)batch * 256 * mblk + inner;

  int tx = tid & 15, ty = tid >> 4;
  int lk = tid >> 6;
  int lm = tid & 63;
  float acc[4][4] = {};

  for (int kc = 0; kc < 256; kc += 32) {
    __syncthreads();
#pragma unroll
    for (int r = 0; r < 8; r++) {
      int kk = lk + r * 4;
      As[kk * 64 + lm] = Ab[(size_t)(kc + kk) * mblk + lm];
      Ws[kk * 64 + lm] = Wt[(kc + kk) * 256 + n0 + lm];
    }
    __syncthreads();
#pragma unroll
    for (int kk = 0; kk < 32; kk++) {
      float4 av = *(const float4*)&As[kk * 64 + ty * 4];
      float4 wv = *(const float4*)&Ws[kk * 64 + tx * 4];
      float a_[4] = {av.x, av.y, av.z, av.w};
      float w_[4] = {wv.x, wv.y, wv.z, wv.w};
#pragma unroll
      for (int ii = 0; ii < 4; ii++)
#pragma unroll
        for (int jj = 0; jj < 4; jj++) acc[ii][jj] += a_[ii] * w_[jj];
    }
  }

#pragma unroll
  for (int ii = 0; ii < 4; ii++) {
    int m = m0 + ty * 4 + ii;
#pragma unroll
    for (int jj = 0; jj < 4; jj++) {
      int n = n0 + tx * 4 + jj;
      Cout[(size_t)m * 256 + n] = acc[ii][jj] + bias[n];
    }
  }
}

// ---------------------------------------------------------------------------
// K3: attention row softmax. One wave per (b, head, i).
// ---------------------------------------------------------------------------
__global__ __launch_bounds__(64) void k_attn(const float* __restrict__ q,
                                             const float* __restrict__ k,
                                             const float* __restrict__ Bbias,
                                             float* __restrict__ attn,
                                             float scale) {
  int bx = blockIdx.x;
  int i = bx & 63, hd = (bx >> 6) & 7, b = bx >> 9;
  int j = threadIdx.x;
  __shared__ float qs[32];
  if (j < 32) qs[j] = q[(size_t)(b * 64 + i) * 256 + hd * 32 + j];
  __syncthreads();
  const float* kp = k + (size_t)(b * 64 + j) * 256 + hd * 32;
  float dot = 0.f;
#pragma unroll
  for (int d = 0; d < 32; d++) dot += qs[d] * kp[d];
  float logit = dot * scale + Bbias[(hd * 64 + i) * 64 + j];
  float mx = logit;
#pragma unroll
  for (int off = 32; off > 0; off >>= 1)
    mx = fmaxf(mx, __shfl_xor(mx, off, 64));
  float e = __expf(logit - mx);
  float sum = e;
#pragma unroll
  for (int off = 32; off > 0; off >>= 1) sum += __shfl_xor(sum, off, 64);
  attn[(size_t)((b * 8 + hd) * 64 + i) * 64 + j] = e / sum;
}

// ---------------------------------------------------------------------------
// K5a: r1[b][hd][h][w*32+dv] = sum_j attn_h[.,h,j] * vlin[(b,j,w)][hd*32+dv]
// vlin bf16 in, r1 bf16 out; fp32 math.
// ---------------------------------------------------------------------------
__global__ __launch_bounds__(256) void k_av(const float* __restrict__ attn,
                                            const ushort* __restrict__ vlin,
                                            ushort* __restrict__ r1) {
  __shared__ __align__(16) float As[64 * 65];
  __shared__ __align__(16) float Bs[64 * 64];

  int bx = blockIdx.x;
  int cc = bx & 31, hd = (bx >> 5) & 7, b = bx >> 8;
  int tid = threadIdx.x;
  int l = tid & 63, g = tid >> 6;

  const float* ap = attn + (size_t)(b * 8 + hd) * 4096;
#pragma unroll
  for (int r = 0; r < 16; r++) {
    int i = g + r * 4;
    As[l * 65 + i] = ap[i * 64 + l];
  }
  int colg0 = cc * 64;
#pragma unroll
  for (int r = 0; r < 16; r++) {
    int j = g + r * 4;
    int colg = colg0 + l;
    int w = colg >> 5, dv = colg & 31;
    Bs[j * 64 + l] =
        bf2f(vlin[(size_t)(b * 4096 + j * 64 + w) * 256 + hd * 32 + dv]);
  }
  __syncthreads();

  int tx = tid & 15, ty = tid >> 4;
  float acc[4][4] = {};
  for (int j = 0; j < 64; j++) {
    float4 bv = *(const float4*)&Bs[j * 64 + tx * 4];
    float b_[4] = {bv.x, bv.y, bv.z, bv.w};
    float a_[4];
#pragma unroll
    for (int ii = 0; ii < 4; ii++) a_[ii] = As[j * 65 + ty * 4 + ii];
#pragma unroll
    for (int ii = 0; ii < 4; ii++)
#pragma unroll
      for (int jj = 0; jj < 4; jj++) acc[ii][jj] += a_[ii] * b_[jj];
  }

  ushort* rp = r1 + (size_t)(b * 8 + hd) * 64 * 2048;
#pragma unroll
  for (int ii = 0; ii < 4; ii++) {
    int row = ty * 4 + ii;
#pragma unroll
    for (int jj = 0; jj < 4; jj++)
      rp[(size_t)row * 2048 + colg0 + tx * 4 + jj] = f2bf(acc[ii][jj]);
  }
}

// ---------------------------------------------------------------------------
// K5b: yT[(b*4096 + h*64 + w')][hd*32+dv] = sum_w r1[b,hd,h,w*32+dv]*attnw[w][w']
// Output directly in [pix][c] bf16 layout for the fc_o MFMA GEMM.
// ---------------------------------------------------------------------------
__global__ __launch_bounds__(256) void k_rw(const ushort* __restrict__ r1,
                                            const float* __restrict__ attnw,
                                            ushort* __restrict__ yT) {
  __shared__ __align__(16) float rr[2048];
  __shared__ __align__(16) float aw[4096];

  int bx = blockIdx.x;
  int h = bx & 63, hd = (bx >> 6) & 7, b = bx >> 9;
  int tid = threadIdx.x;

  const ushort* rp = r1 + (size_t)((b * 8 + hd) * 64 + h) * 2048;
#pragma unroll
  for (int r = 0; r < 8; r++) rr[tid + r * 256] = bf2f(rp[tid + r * 256]);
  const float* ap = attnw + (size_t)(b * 8 + hd) * 4096;
#pragma unroll
  for (int r = 0; r < 16; r++) aw[tid + r * 256] = ap[tid + r * 256];
  __syncthreads();

  int wp = tid & 63;
  int dv0 = (tid >> 6) * 8;
  float acc[8] = {};
  for (int w = 0; w < 64; w++) {
    float a = aw[w * 64 + wp];
    float4 r4a = *(const float4*)&rr[w * 32 + dv0];
    float4 r4b = *(const float4*)&rr[w * 32 + dv0 + 4];
    float rv[8] = {r4a.x, r4a.y, r4a.z, r4a.w, r4b.x, r4b.y, r4b.z, r4b.w};
#pragma unroll
    for (int d = 0; d < 8; d++) acc[d] += a * rv[d];
  }

  ushort* yp = yT + (size_t)(b * 4096 + h * 64 + wp) * 256 + hd * 32 + dv0;
#pragma unroll
  for (int d = 0; d < 8; d++) yp[d] = f2bf(acc[d]);
}

// ---------------------------------------------------------------------------
extern "C" void kernel_launch(void* const* d_in, const int* in_sizes, int n_in,
                              void* d_out, int out_size, void* d_ws,
                              size_t ws_size, hipStream_t stream) {
  const float* x      = (const float*)d_in[0];
  const float* dwqh_w = (const float*)d_in[1];
  const float* dwqh_b = (const float*)d_in[2];
  const float* fcqh_w = (const float*)d_in[3];
  const float* fcqh_b = (const float*)d_in[4];
  const float* dwkh_w = (const float*)d_in[5];
  const float* dwkh_b = (const float*)d_in[6];
  const float* fckh_w = (const float*)d_in[7];
  const float* fckh_b = (const float*)d_in[8];
  const float* Bh     = (const float*)d_in[9];
  const float* dwv_w  = (const float*)d_in[10];
  const float* dwv_b  = (const float*)d_in[11];
  const float* fcv_w  = (const float*)d_in[12];
  const float* fcv_b  = (const float*)d_in[13];
  const float* dwqw_w = (const float*)d_in[14];
  const float* dwqw_b = (const float*)d_in[15];
  const float* fcqw_w = (const float*)d_in[16];
  const float* fcqw_b = (const float*)d_in[17];
  const float* dwkw_w = (const float*)d_in[18];
  const float* dwkw_b = (const float*)d_in[19];
  const float* fckw_w = (const float*)d_in[20];
  const float* fckw_b = (const float*)d_in[21];
  const float* Bw     = (const float*)d_in[22];
  const float* fco_w  = (const float*)d_in[23];
  const float* fco_b  = (const float*)d_in[24];

  char* base = (char*)d_ws;
  // three big bf16 buffers (16.7M elements each), lifetimes interleaved
  ushort* P1 = (ushort*)(base);                  // convV, later r1
  ushort* P2 = (ushort*)(base + 33554432);       // convA, later yT
  ushort* P3 = (ushort*)(base + 67108864);       // vlin
  float*  wt   = (float*)(base + 100663296);     // 4 x 65536 fp32
  ushort* wv_bf = (ushort*)(base + 101711872);   // 65536 bf16
  // wo_bf is wv_bf + 65536 (contiguous, filled by k_cvt)
  float* qhm = (float*)(base + 101974016);
  float* khm = qhm + 262144;
  float* qwm = khm + 262144;
  float* kwm = qwm + 262144;
  float* qhl = kwm + 262144;
  float* khl = qhl + 262144;
  float* qwl = khl + 262144;
  float* kwl = qwl + 262144;
  float* ah  = kwl + 262144;                     // 524288
  float* awt = ah + 524288;                      // 524288
  if (ws_size < 115000000ull) return;  // proven available (round 3 ran with 148MB demanded)

  const float scale = 0.17677669529663687f;  // 32^-0.5

  k_wt<<<1024, 256, 0, stream>>>(fcqh_w, fckh_w, fcqw_w, fckw_w, wt);
  k_cvt<<<512, 256, 0, stream>>>(fcv_w, fco_w, wv_bf);
  k_conv<<<4096, 256, 0, stream>>>(x, dwqh_w, dwqh_b, dwkh_w, dwkh_b, dwv_w,
                                   dwv_b, dwqw_w, dwqw_b, dwkw_w, dwkw_b, P1,
                                   qhm, khm, qwm, kwm);
  k_tr<<<4096, 256, 0, stream>>>(P1, P2);
  k_gemm<<<dim3(16, 4), 256, 0, stream>>>(qhm, wt + 0 * 65536, fcqh_b, qhl, 64);
  k_gemm<<<dim3(16, 4), 256, 0, stream>>>(khm, wt + 1 * 65536, fckh_b, khl, 64);
  k_gemm<<<dim3(16, 4), 256, 0, stream>>>(qwm, wt + 2 * 65536, fcqw_b, qwl, 64);
  k_gemm<<<dim3(16, 4), 256, 0, stream>>>(kwm, wt + 3 * 65536, fckw_b, kwl, 64);
  k_attn<<<8192, 64, 0, stream>>>(qhl, khl, Bh, ah, scale);
  k_attn<<<8192, 64, 0, stream>>>(qwl, kwl, Bw, awt, scale);
  k_mm<1><<<dim3(512, 2), 256, 0, stream>>>(P2, wv_bf, fcv_b, P3);
  k_av<<<4096, 256, 0, stream>>>(ah, P3, P1);
  k_rw<<<8192, 256, 0, stream>>>(P1, awt, P2);
  k_mm<0><<<dim3(512, 2), 256, 0, stream>>>(P2, wv_bf + 65536, fco_b, d_out);
}

// Round 5
// 386.835 us; speedup vs baseline: 1.5692x; 1.1253x over previous
//
#include <hip/hip_runtime.h>
#include <hip/hip_bf16.h>

typedef float f4v __attribute__((ext_vector_type(4)));
typedef short s8v __attribute__((ext_vector_type(8)));
typedef unsigned short u8v __attribute__((ext_vector_type(8)));

__device__ __forceinline__ float bf2f(ushort u) {
  union { unsigned int i; float f; } c; c.i = ((unsigned int)u) << 16;
  return c.f;
}
__device__ __forceinline__ ushort f2bf(float f) {
  union { ushort s; __hip_bfloat16 h; } c; c.h = __float2bfloat16(f);
  return c.s;
}

// ---------------------------------------------------------------------------
// K_prep: bx<1024: transpose four fp32 weights [o][c]->[c][o] into wt.
//         bx>=1024: cast fc_v|fc_o to bf16 keeping [n][k] (k-contig) layout.
// ---------------------------------------------------------------------------
__global__ __launch_bounds__(256) void k_prep(const float* __restrict__ w0,
                                              const float* __restrict__ w1,
                                              const float* __restrict__ w2,
                                              const float* __restrict__ w3,
                                              const float* __restrict__ wv,
                                              const float* __restrict__ wo,
                                              float* __restrict__ wt,
                                              ushort* __restrict__ wbf) {
  int bx = blockIdx.x;
  int tid = threadIdx.x;
  if (bx < 1024) {
    int mat = bx >> 8, o = bx & 255;
    const float* p = mat == 0 ? w0 : mat == 1 ? w1 : mat == 2 ? w2 : w3;
    wt[(size_t)mat * 65536 + (size_t)tid * 256 + o] = p[o * 256 + tid];
  } else {
    int idx = (bx - 1024) * 256 + tid;  // 0..131071
    const float* src = (idx >> 16) ? wo : wv;
    wbf[idx] = f2bf(src[idx & 65535]);
  }
}

// ---------------------------------------------------------------------------
// K1: fused 5x depthwise 3x3 conv per (b,c) plane + pooled means.
// convV (bf16): [b][c][pix]  (k-major / A^T for the v-GEMM AT mode)
// qhm/khm/qwm/kwm (fp32): [b][c][64]
// Thread layout: wgrp=tid&15 (4 w-cols each), hq=tid>>4; h = hq+16q, q<4.
// ---------------------------------------------------------------------------
__global__ __launch_bounds__(256) void k_conv(
    const float* __restrict__ x,
    const float* __restrict__ wqh, const float* __restrict__ bqh,
    const float* __restrict__ wkh, const float* __restrict__ bkh,
    const float* __restrict__ wv,  const float* __restrict__ bv,
    const float* __restrict__ wqw, const float* __restrict__ bqw,
    const float* __restrict__ wkw, const float* __restrict__ bkw,
    ushort* __restrict__ convV,
    float* __restrict__ qhm, float* __restrict__ khm,
    float* __restrict__ qwm, float* __restrict__ kwm) {
  // padded plane: padded row pr=src r+1 at pr*72; src col c at pr*72+4+c
  __shared__ float xs[66 * 72];
  __shared__ float wl[5][9];
  __shared__ float bl[5];
  __shared__ float redc[2][16][64];

  int bx = blockIdx.x;
  int b = bx >> 8;
  int c = bx & 255;
  int tid = threadIdx.x;

  const float* xp = x + (size_t)(b * 256 + c) * 4096;
#pragma unroll
  for (int i = 0; i < 4; i++) {
    int flat = tid + i * 256;          // 0..1023
    int r = flat >> 4, c4 = (flat & 15) * 4;
    float4 v = *(const float4*)(xp + r * 64 + c4);
    *(float4*)&xs[(r + 1) * 72 + 4 + c4] = v;
  }
  if (tid < 72) { xs[tid] = 0.f; xs[65 * 72 + tid] = 0.f; }
  if (tid < 64) { xs[(tid + 1) * 72 + 3] = 0.f; xs[(tid + 1) * 72 + 68] = 0.f; }
  if (tid >= 128 && tid < 173) {
    int t = tid - 128;
    int cw = t / 9, wi = t % 9;
    const float* wp = cw == 0 ? wqh : cw == 1 ? wkh : cw == 2 ? wv
                    : cw == 3 ? wqw : wkw;
    wl[cw][wi] = wp[c * 9 + wi];
  } else if (tid >= 173 && tid < 178) {
    int cw = tid - 173;
    const float* bp = cw == 0 ? bqh : cw == 1 ? bkh : cw == 2 ? bv
                    : cw == 3 ? bqw : bkw;
    bl[cw] = bp[c];
  }
  __syncthreads();

  int wgrp = tid & 15, hq = tid >> 4;
  int w4 = wgrp * 4;
  float cs3[4] = {0.f, 0.f, 0.f, 0.f}, cs4[4] = {0.f, 0.f, 0.f, 0.f};

#pragma unroll
  for (int q = 0; q < 4; q++) {
    int h = hq + q * 16;
    float win[3][6];
#pragma unroll
    for (int ky = 0; ky < 3; ky++)
#pragma unroll
      for (int kk = 0; kk < 6; kk++)
        win[ky][kk] = xs[(h + ky) * 72 + 3 + w4 + kk];

    float o0[4], o1[4], o2[4], o3[4], o4[4];
#pragma unroll
    for (int dw = 0; dw < 4; dw++) {
      float a0 = 0.f, a1 = 0.f, a2 = 0.f, a3 = 0.f, a4 = 0.f;
#pragma unroll
      for (int ky = 0; ky < 3; ky++)
#pragma unroll
        for (int kx = 0; kx < 3; kx++) {
          float xv = win[ky][dw + kx];
          int wi = ky * 3 + kx;
          a0 += xv * wl[0][wi];
          a1 += xv * wl[1][wi];
          a2 += xv * wl[2][wi];
          a3 += xv * wl[3][wi];
          a4 += xv * wl[4][wi];
        }
      o0[dw] = a0; o1[dw] = a1; o2[dw] = a2; o3[dw] = a3; o4[dw] = a4;
    }

    // convV (v-conv) store, 4 bf16 = 8B
    ushort pk[4];
#pragma unroll
    for (int dw = 0; dw < 4; dw++) pk[dw] = f2bf(o2[dw] + bl[2]);
    *(uint2*)&convV[(size_t)(b * 256 + c) * 4096 + h * 64 + w4] =
        *(uint2*)pk;

    // row means (qh,kh): local 4-sum + 16-lane xor-tree
    float s0 = (o0[0] + o0[1]) + (o0[2] + o0[3]);
    float s1 = (o1[0] + o1[1]) + (o1[2] + o1[3]);
#pragma unroll
    for (int off = 1; off < 16; off <<= 1) {
      s0 += __shfl_xor(s0, off, 64);
      s1 += __shfl_xor(s1, off, 64);
    }
    if (wgrp == 0) {
      qhm[(size_t)(b * 256 + c) * 64 + h] = s0 * (1.f / 64.f) + bl[0];
      khm[(size_t)(b * 256 + c) * 64 + h] = s1 * (1.f / 64.f) + bl[1];
    }

#pragma unroll
    for (int dw = 0; dw < 4; dw++) { cs3[dw] += o3[dw]; cs4[dw] += o4[dw]; }
  }

  *(float4*)&redc[0][hq][w4] = *(float4*)cs3;
  *(float4*)&redc[1][hq][w4] = *(float4*)cs4;
  __syncthreads();
  if (tid < 128) {
    int cv = tid >> 6, w = tid & 63;
    float s = 0.f;
#pragma unroll
    for (int h2 = 0; h2 < 16; h2++) s += redc[cv][h2][w];
    float* dst = cv ? kwm : qwm;
    dst[(size_t)(b * 256 + c) * 64 + w] = s * (1.f / 64.f) + bl[3 + cv];
  }
}

// ---------------------------------------------------------------------------
// K2: bf16 MFMA GEMM. out[m][n] = sum_k A[m][k] * W[n][k] + bias[n]
// AT==0: A is [M][256] row-major bf16 (k contiguous).
// AT==1: A is [b][k=256][m=4096] (convV layout); staged via LDS transpose.
// W: [256][256] bf16 k-contig. 128x128 tile, 4 waves, 4x4 mfma_16x16x32_bf16.
// ---------------------------------------------------------------------------
template <int OUT_BF16, int AT>
__global__ __launch_bounds__(256) void k_mm(const ushort* __restrict__ A,
                                            const ushort* __restrict__ W,
                                            const float* __restrict__ bias,
                                            void* __restrict__ out) {
  __shared__ __align__(16) ushort As[128 * 40];
  __shared__ __align__(16) ushort Bs[128 * 40];

  int m0 = blockIdx.x * 128;
  int n0 = blockIdx.y * 128;
  int tid = threadIdx.x;
  int lane = tid & 63, wave = tid >> 6;
  int wm = (wave & 1) * 64, wn = (wave >> 1) * 64;
  int tm = lane & 15, quad = lane >> 4;

  const ushort* Abase;
  if (AT) {
    Abase = A + (size_t)(m0 >> 12) * (256 * 4096) + (m0 & 4095);
  } else {
    Abase = A + (size_t)m0 * 256;
  }

  f4v acc[4][4] = {};

  for (int kc = 0; kc < 256; kc += 32) {
    __syncthreads();
    if (AT) {
      // A^T tile: 32 k-rows x 128 m; thread: kr2=(tid&15)*2, mg=tid>>4
      int kr2 = (tid & 15) * 2, mg = tid >> 4;
      u8v v0 = *(const u8v*)&Abase[(size_t)(kc + kr2) * 4096 + mg * 8];
      u8v v1 = *(const u8v*)&Abase[(size_t)(kc + kr2 + 1) * 4096 + mg * 8];
#pragma unroll
      for (int j = 0; j < 8; j++) {
        ushort pr[2] = {v0[j], v1[j]};
        *(uint*)&As[(mg * 8 + j) * 40 + kr2] = *(uint*)pr;
      }
#pragma unroll
      for (int h = 0; h < 2; h++) {
        int ch = tid + h * 256;
        int mr = ch >> 2, k8 = (ch & 3) * 8;
        *(float4*)&Bs[mr * 40 + k8] =
            *(const float4*)&W[(size_t)(n0 + mr) * 256 + kc + k8];
      }
    } else {
#pragma unroll
      for (int h = 0; h < 2; h++) {
        int ch = tid + h * 256;
        int mr = ch >> 2, k8 = (ch & 3) * 8;
        *(float4*)&As[mr * 40 + k8] =
            *(const float4*)&Abase[(size_t)mr * 256 + kc + k8];
        *(float4*)&Bs[mr * 40 + k8] =
            *(const float4*)&W[(size_t)(n0 + mr) * 256 + kc + k8];
      }
    }
    __syncthreads();

    s8v a[4], bfr[4];
#pragma unroll
    for (int mi = 0; mi < 4; mi++)
      a[mi] = *(const s8v*)&As[(wm + mi * 16 + tm) * 40 + quad * 8];
#pragma unroll
    for (int ni = 0; ni < 4; ni++)
      bfr[ni] = *(const s8v*)&Bs[(wn + ni * 16 + tm) * 40 + quad * 8];
#pragma unroll
    for (int mi = 0; mi < 4; mi++)
#pragma unroll
      for (int ni = 0; ni < 4; ni++)
        acc[mi][ni] = __builtin_amdgcn_mfma_f32_16x16x32_bf16(
            a[mi], bfr[ni], acc[mi][ni], 0, 0, 0);
  }

  // C/D layout: col = lane&15, row = quad*4 + reg
#pragma unroll
  for (int mi = 0; mi < 4; mi++) {
#pragma unroll
    for (int ni = 0; ni < 4; ni++) {
      int col = n0 + wn + ni * 16 + tm;
      float bv = bias[col];
#pragma unroll
      for (int r = 0; r < 4; r++) {
        int row = m0 + wm + mi * 16 + quad * 4 + r;
        float v = acc[mi][ni][r] + bv;
        if (OUT_BF16)
          ((ushort*)out)[(size_t)row * 256 + col] = f2bf(v);
        else
          ((float*)out)[(size_t)row * 256 + col] = v;
      }
    }
  }
}

// ---------------------------------------------------------------------------
// Small fp32 GEMM for pooled q/k linears, all four fused via blockIdx.z.
// C = At^T * Wt + bias, At batched k-major with mblk=64.
// ---------------------------------------------------------------------------
__global__ __launch_bounds__(256) void k_gemm4(
    const float* __restrict__ s0, const float* __restrict__ s1,
    const float* __restrict__ s2, const float* __restrict__ s3,
    const float* __restrict__ wt,
    const float* __restrict__ b0, const float* __restrict__ b1,
    const float* __restrict__ b2, const float* __restrict__ b3,
    float* __restrict__ d0, float* __restrict__ d1,
    float* __restrict__ d2, float* __restrict__ d3) {
  __shared__ __align__(16) float As[32 * 64];
  __shared__ __align__(16) float Ws[32 * 64];

  int z = blockIdx.z;
  const float* At = z == 0 ? s0 : z == 1 ? s1 : z == 2 ? s2 : s3;
  const float* Wt = wt + (size_t)z * 65536;
  const float* bias = z == 0 ? b0 : z == 1 ? b1 : z == 2 ? b2 : b3;
  float* Cout = z == 0 ? d0 : z == 1 ? d1 : z == 2 ? d2 : d3;

  int m0 = blockIdx.x * 64;
  int n0 = blockIdx.y * 64;
  int tid = threadIdx.x;
  const float* Ab = At + (size_t)(m0 >> 6) * 256 * 64;

  int tx = tid & 15, ty = tid >> 4;
  int lk = tid >> 6;
  int lm = tid & 63;
  float acc[4][4] = {};

  for (int kc = 0; kc < 256; kc += 32) {
    __syncthreads();
#pragma unroll
    for (int r = 0; r < 8; r++) {
      int kk = lk + r * 4;
      As[kk * 64 + lm] = Ab[(size_t)(kc + kk) * 64 + lm];
      Ws[kk * 64 + lm] = Wt[(kc + kk) * 256 + n0 + lm];
    }
    __syncthreads();
#pragma unroll
    for (int kk = 0; kk < 32; kk++) {
      float4 av = *(const float4*)&As[kk * 64 + ty * 4];
      float4 wv = *(const float4*)&Ws[kk * 64 + tx * 4];
      float a_[4] = {av.x, av.y, av.z, av.w};
      float w_[4] = {wv.x, wv.y, wv.z, wv.w};
#pragma unroll
      for (int ii = 0; ii < 4; ii++)
#pragma unroll
        for (int jj = 0; jj < 4; jj++) acc[ii][jj] += a_[ii] * w_[jj];
    }
  }

#pragma unroll
  for (int ii = 0; ii < 4; ii++) {
    int m = m0 + ty * 4 + ii;
#pragma unroll
    for (int jj = 0; jj < 4; jj++) {
      int n = n0 + tx * 4 + jj;
      Cout[(size_t)m * 256 + n] = acc[ii][jj] + bias[n];
    }
  }
}

// ---------------------------------------------------------------------------
// K3: attention softmax, both axes fused. 256 threads = 4 rows per block.
// attn[b][hd][i][j] = softmax_j(scale*q.k + Bias[hd][i][j])
// ---------------------------------------------------------------------------
__global__ __launch_bounds__(256) void k_attn(
    const float* __restrict__ qh, const float* __restrict__ kh,
    const float* __restrict__ Bh, float* __restrict__ ah,
    const float* __restrict__ qw, const float* __restrict__ kw,
    const float* __restrict__ Bw, float* __restrict__ aw, float scale) {
  __shared__ float qs[4][32];
  __shared__ float ks[64 * 33];

  int bx = blockIdx.x;
  int setw = bx >> 11;
  int rem = bx & 2047;
  int ig = rem & 15, hd = (rem >> 4) & 7, b = rem >> 7;
  int tid = threadIdx.x;
  int wave = tid >> 6, lane = tid & 63;
  int i = ig * 4 + wave;

  const float* q = setw ? qw : qh;
  const float* k = setw ? kw : kh;
  const float* Bb = setw ? Bw : Bh;
  float* attn = setw ? aw : ah;

  if (lane < 32) qs[wave][lane] = q[(size_t)(b * 64 + i) * 256 + hd * 32 + lane];
#pragma unroll
  for (int it = 0; it < 8; it++) {
    int f = tid + it * 256;
    int j = f >> 5, d = f & 31;
    ks[j * 33 + d] = k[(size_t)(b * 64 + j) * 256 + hd * 32 + d];
  }
  __syncthreads();

  int j = lane;
  float dot = 0.f;
#pragma unroll
  for (int d = 0; d < 32; d++) dot += qs[wave][d] * ks[j * 33 + d];
  float logit = dot * scale + Bb[(hd * 64 + i) * 64 + j];
  float mx = logit;
#pragma unroll
  for (int off = 32; off > 0; off >>= 1)
    mx = fmaxf(mx, __shfl_xor(mx, off, 64));
  float e = __expf(logit - mx);
  float sum = e;
#pragma unroll
  for (int off = 32; off > 0; off >>= 1) sum += __shfl_xor(sum, off, 64);
  attn[(size_t)((b * 8 + hd) * 64 + i) * 64 + j] = e / sum;
}

// ---------------------------------------------------------------------------
// K5a: r1[b][hd][h][w*32+dv] = sum_j attn_h[.,h,j] * vlin[(b,j,w)][hd*32+dv]
// ---------------------------------------------------------------------------
__global__ __launch_bounds__(256) void k_av(const float* __restrict__ attn,
                                            const ushort* __restrict__ vlin,
                                            ushort* __restrict__ r1) {
  __shared__ __align__(16) float As[64 * 65];
  __shared__ __align__(16) float Bs[64 * 64];

  int bx = blockIdx.x;
  int cc = bx & 31, hd = (bx >> 5) & 7, b = bx >> 8;
  int tid = threadIdx.x;
  int l = tid & 63, g = tid >> 6;

  const float* ap = attn + (size_t)(b * 8 + hd) * 4096;
#pragma unroll
  for (int r = 0; r < 16; r++) {
    int i = g + r * 4;
    As[l * 65 + i] = ap[i * 64 + l];
  }
  int colg0 = cc * 64;
#pragma unroll
  for (int r = 0; r < 8; r++) {
    int f = tid + r * 256;                 // 0..2047
    int j = f >> 5, p2 = f & 31;
    int colg = colg0 + p2 * 2;
    int w = colg >> 5, dv = colg & 31;     // dv even
    uint u = *(const uint*)&vlin[(size_t)(b * 4096 + j * 64 + w) * 256 +
                                 hd * 32 + dv];
    Bs[j * 64 + p2 * 2] = bf2f((ushort)(u & 0xffff));
    Bs[j * 64 + p2 * 2 + 1] = bf2f((ushort)(u >> 16));
  }
  __syncthreads();

  int tx = tid & 15, ty = tid >> 4;
  float acc[4][4] = {};
  for (int j = 0; j < 64; j++) {
    float4 bv = *(const float4*)&Bs[j * 64 + tx * 4];
    float b_[4] = {bv.x, bv.y, bv.z, bv.w};
    float a_[4];
#pragma unroll
    for (int ii = 0; ii < 4; ii++) a_[ii] = As[j * 65 + ty * 4 + ii];
#pragma unroll
    for (int ii = 0; ii < 4; ii++)
#pragma unroll
      for (int jj = 0; jj < 4; jj++) acc[ii][jj] += a_[ii] * b_[jj];
  }

  ushort* rp = r1 + (size_t)(b * 8 + hd) * 64 * 2048;
#pragma unroll
  for (int ii = 0; ii < 4; ii++) {
    int row = ty * 4 + ii;
    ushort pk[4];
#pragma unroll
    for (int jj = 0; jj < 4; jj++) pk[jj] = f2bf(acc[ii][jj]);
    *(uint2*)&rp[(size_t)row * 2048 + colg0 + tx * 4] = *(uint2*)pk;
  }
}

// ---------------------------------------------------------------------------
// K5b: yT[(b*4096+h*64+w')][hd*32+dv] = sum_w r1[b,hd,h,w*32+dv]*attnw[w][w']
// ---------------------------------------------------------------------------
__global__ __launch_bounds__(256) void k_rw(const ushort* __restrict__ r1,
                                            const float* __restrict__ attnw,
                                            ushort* __restrict__ yT) {
  __shared__ __align__(16) float rr[2048];
  __shared__ __align__(16) float aw[4096];

  int bx = blockIdx.x;
  int h = bx & 63, hd = (bx >> 6) & 7, b = bx >> 9;
  int tid = threadIdx.x;

  const uint* rp = (const uint*)(r1 + (size_t)((b * 8 + hd) * 64 + h) * 2048);
#pragma unroll
  for (int r = 0; r < 4; r++) {
    uint u = rp[tid + r * 256];
    rr[2 * (tid + r * 256)] = bf2f((ushort)(u & 0xffff));
    rr[2 * (tid + r * 256) + 1] = bf2f((ushort)(u >> 16));
  }
  const float* ap = attnw + (size_t)(b * 8 + hd) * 4096;
#pragma unroll
  for (int r = 0; r < 4; r++)
    *(float4*)&aw[4 * (tid + r * 256)] = *(const float4*)&ap[4 * (tid + r * 256)];
  __syncthreads();

  int wp = tid & 63;
  int dv0 = (tid >> 6) * 8;
  float acc[8] = {};
  for (int w = 0; w < 64; w++) {
    float a = aw[w * 64 + wp];
    float4 r4a = *(const float4*)&rr[w * 32 + dv0];
    float4 r4b = *(const float4*)&rr[w * 32 + dv0 + 4];
    float rv[8] = {r4a.x, r4a.y, r4a.z, r4a.w, r4b.x, r4b.y, r4b.z, r4b.w};
#pragma unroll
    for (int d = 0; d < 8; d++) acc[d] += a * rv[d];
  }

  ushort* yp = yT + (size_t)(b * 4096 + h * 64 + wp) * 256 + hd * 32 + dv0;
  ushort pk[8];
#pragma unroll
  for (int d = 0; d < 8; d++) pk[d] = f2bf(acc[d]);
  *(uint4*)yp = *(uint4*)pk;
}

// ---------------------------------------------------------------------------
extern "C" void kernel_launch(void* const* d_in, const int* in_sizes, int n_in,
                              void* d_out, int out_size, void* d_ws,
                              size_t ws_size, hipStream_t stream) {
  const float* x      = (const float*)d_in[0];
  const float* dwqh_w = (const float*)d_in[1];
  const float* dwqh_b = (const float*)d_in[2];
  const float* fcqh_w = (const float*)d_in[3];
  const float* fcqh_b = (const float*)d_in[4];
  const float* dwkh_w = (const float*)d_in[5];
  const float* dwkh_b = (const float*)d_in[6];
  const float* fckh_w = (const float*)d_in[7];
  const float* fckh_b = (const float*)d_in[8];
  const float* Bh     = (const float*)d_in[9];
  const float* dwv_w  = (const float*)d_in[10];
  const float* dwv_b  = (const float*)d_in[11];
  const float* fcv_w  = (const float*)d_in[12];
  const float* fcv_b  = (const float*)d_in[13];
  const float* dwqw_w = (const float*)d_in[14];
  const float* dwqw_b = (const float*)d_in[15];
  const float* fcqw_w = (const float*)d_in[16];
  const float* fcqw_b = (const float*)d_in[17];
  const float* dwkw_w = (const float*)d_in[18];
  const float* dwkw_b = (const float*)d_in[19];
  const float* fckw_w = (const float*)d_in[20];
  const float* fckw_b = (const float*)d_in[21];
  const float* Bw     = (const float*)d_in[22];
  const float* fco_w  = (const float*)d_in[23];
  const float* fco_b  = (const float*)d_in[24];

  char* base = (char*)d_ws;
  ushort* P1 = (ushort*)(base);                  // convV, later r1
  ushort* P2 = (ushort*)(base + 33554432);       // yT
  ushort* P3 = (ushort*)(base + 67108864);       // vlin
  float*  wt   = (float*)(base + 100663296);     // 4 x 65536 fp32
  ushort* wv_bf = (ushort*)(base + 101711872);   // 2 x 65536 bf16
  float* qhm = (float*)(base + 101974016);
  float* khm = qhm + 262144;
  float* qwm = khm + 262144;
  float* kwm = qwm + 262144;
  float* qhl = kwm + 262144;
  float* khl = qhl + 262144;
  float* qwl = khl + 262144;
  float* kwl = qwl + 262144;
  float* ah  = kwl + 262144;                     // 524288
  float* awt = ah + 524288;                      // 524288
  if (ws_size < 115000000ull) return;

  const float scale = 0.17677669529663687f;  // 32^-0.5

  k_prep<<<1536, 256, 0, stream>>>(fcqh_w, fckh_w, fcqw_w, fckw_w, fcv_w,
                                   fco_w, wt, wv_bf);
  k_conv<<<4096, 256, 0, stream>>>(x, dwqh_w, dwqh_b, dwkh_w, dwkh_b, dwv_w,
                                   dwv_b, dwqw_w, dwqw_b, dwkw_w, dwkw_b, P1,
                                   qhm, khm, qwm, kwm);
  k_gemm4<<<dim3(16, 4, 4), 256, 0, stream>>>(qhm, khm, qwm, kwm, wt, fcqh_b,
                                              fckh_b, fcqw_b, fckw_b, qhl, khl,
                                              qwl, kwl);
  k_attn<<<4096, 256, 0, stream>>>(qhl, khl, Bh, ah, qwl, kwl, Bw, awt, scale);
  k_mm<1, 1><<<dim3(512, 2), 256, 0, stream>>>(P1, wv_bf, fcv_b, P3);
  k_av<<<4096, 256, 0, stream>>>(ah, P3, P1);
  k_rw<<<8192, 256, 0, stream>>>(P1, awt, P2);
  k_mm<0, 0><<<dim3(512, 2), 256, 0, stream>>>(P2, wv_bf + 65536, fco_b, d_out);
}

// Round 6
// 321.603 us; speedup vs baseline: 1.8874x; 1.2028x over previous
//
#include <hip/hip_runtime.h>
#include <hip/hip_bf16.h>

typedef float f4v __attribute__((ext_vector_type(4)));
typedef short s8v __attribute__((ext_vector_type(8)));
typedef unsigned short u8v __attribute__((ext_vector_type(8)));

__device__ __forceinline__ float bf2f(ushort u) {
  union { unsigned int i; float f; } c; c.i = ((unsigned int)u) << 16;
  return c.f;
}
__device__ __forceinline__ ushort f2bf(float f) {
  union { ushort s; __hip_bfloat16 h; } c; c.h = __float2bfloat16(f);
  return c.s;
}

// ---------------------------------------------------------------------------
// K_prep: bx<1024: transpose four fp32 weights [o][c]->[c][o] into wt.
//         bx>=1024: cast fc_v|fc_o to bf16 keeping [n][k] (k-contig) layout.
// ---------------------------------------------------------------------------
__global__ __launch_bounds__(256) void k_prep(const float* __restrict__ w0,
                                              const float* __restrict__ w1,
                                              const float* __restrict__ w2,
                                              const float* __restrict__ w3,
                                              const float* __restrict__ wv,
                                              const float* __restrict__ wo,
                                              float* __restrict__ wt,
                                              ushort* __restrict__ wbf) {
  int bx = blockIdx.x;
  int tid = threadIdx.x;
  if (bx < 1024) {
    int mat = bx >> 8, o = bx & 255;
    const float* p = mat == 0 ? w0 : mat == 1 ? w1 : mat == 2 ? w2 : w3;
    wt[(size_t)mat * 65536 + (size_t)tid * 256 + o] = p[o * 256 + tid];
  } else {
    int idx = (bx - 1024) * 256 + tid;  // 0..131071
    const float* src = (idx >> 16) ? wo : wv;
    wbf[idx] = f2bf(src[idx & 65535]);
  }
}

// ---------------------------------------------------------------------------
// K1: per (b,c) plane: v-conv per pixel + ALL four pooled conv means computed
// from row/col sums of x (conv is linear; mean over an axis only needs
// rowsum/colsum + edge corrections). No in-loop shuffles, w=lane mapping,
// rolling 3x3 window, stride-68 LDS (conflict-free, float4-aligned staging).
// convV (bf16): [b][c][pix]; qhm/khm/qwm/kwm (fp32): [b][c][64]
// ---------------------------------------------------------------------------
__global__ __launch_bounds__(256) void k_conv(
    const float* __restrict__ x,
    const float* __restrict__ wqh, const float* __restrict__ bqh,
    const float* __restrict__ wkh, const float* __restrict__ bkh,
    const float* __restrict__ wv,  const float* __restrict__ bv,
    const float* __restrict__ wqw, const float* __restrict__ bqw,
    const float* __restrict__ wkw, const float* __restrict__ bkw,
    ushort* __restrict__ convV,
    float* __restrict__ qhm, float* __restrict__ khm,
    float* __restrict__ qwm, float* __restrict__ kwm) {
  // x[r][c] at xs[(r+1)*68 + 4 + c]; halo col -1 at offset 3, col 64 at 68
  // (spills into next row's unused offset 0 -- harmless, zeroed).
  __shared__ float xs[68 * 68];
  __shared__ float wl[5][9];
  __shared__ float bl[5];

  int bx = blockIdx.x;
  int b = bx >> 8;
  int c = bx & 255;
  int tid = threadIdx.x;
  int lane = tid & 63, wave = tid >> 6;

  const float* xp = x + (size_t)(b * 256 + c) * 4096;
#pragma unroll
  for (int i = 0; i < 4; i++) {
    int flat = tid + i * 256;          // 0..1023
    int r = flat >> 4, c4 = (flat & 15) * 4;
    float4 v = *(const float4*)(xp + r * 64 + c4);
    *(float4*)&xs[(r + 1) * 68 + 4 + c4] = v;
  }
  // zero top/bottom padded rows (+ right-halo spill cells)
  if (tid < 72) { xs[tid] = 0.f; xs[65 * 68 + tid] = 0.f; }
  // zero side halos for padded rows 1..64
  if (tid >= 72 && tid < 200) {
    int t = tid - 72;
    int pr = (t & 63) + 1, side = t >> 6;
    xs[pr * 68 + (side ? 68 : 3)] = 0.f;
  }
  if (tid >= 200 && tid < 245) {
    int t = tid - 200;
    int cw = t / 9, wi = t % 9;
    const float* wp = cw == 0 ? wqh : cw == 1 ? wkh : cw == 2 ? wv
                    : cw == 3 ? wqw : wkw;
    wl[cw][wi] = wp[c * 9 + wi];
  } else if (tid >= 245 && tid < 250) {
    int cw = tid - 245;
    const float* bp = cw == 0 ? bqh : cw == 1 ? bkh : cw == 2 ? bv
                    : cw == 3 ? bqw : bkw;
    bl[cw] = bp[c];
  }
  __syncthreads();

  // ---- v-conv: wave handles rows h0..h0+15, lane = output col ----
  {
    int w = lane;
    int h0 = wave * 16;
    float v0 = wl[2][0], v1 = wl[2][1], v2 = wl[2][2];
    float v3 = wl[2][3], v4 = wl[2][4], v5 = wl[2][5];
    float v6 = wl[2][6], v7 = wl[2][7], v8 = wl[2][8];
    float bvv = bl[2];
    float a00 = xs[h0 * 68 + 3 + w], a01 = xs[h0 * 68 + 4 + w],
          a02 = xs[h0 * 68 + 5 + w];
    float a10 = xs[(h0 + 1) * 68 + 3 + w], a11 = xs[(h0 + 1) * 68 + 4 + w],
          a12 = xs[(h0 + 1) * 68 + 5 + w];
    ushort* cp = convV + (size_t)(b * 256 + c) * 4096 + h0 * 64 + w;
#pragma unroll
    for (int i = 0; i < 16; i++) {
      int pr = h0 + i + 2;
      float a20 = xs[pr * 68 + 3 + w];
      float a21 = xs[pr * 68 + 4 + w];
      float a22 = xs[pr * 68 + 5 + w];
      float acc = bvv;
      acc += a00 * v0 + a01 * v1 + a02 * v2;
      acc += a10 * v3 + a11 * v4 + a12 * v5;
      acc += a20 * v6 + a21 * v7 + a22 * v8;
      cp[i * 64] = f2bf(acc);
      a00 = a10; a01 = a11; a02 = a12;
      a10 = a20; a11 = a21; a12 = a22;
    }
  }

  // ---- pooled means from linearity: wave0 rows, wave1 cols ----
  if (wave == 0) {
    // rowsum + edge cols for row r=lane
    float rs = 0.f, e0 = 0.f, e1 = 0.f;
    const float* rowp = &xs[(lane + 1) * 68 + 4];
#pragma unroll
    for (int i = 0; i < 16; i++) {
      float4 v = *(const float4*)(rowp + i * 4);
      rs += (v.x + v.y) + (v.z + v.w);
      if (i == 0) e0 = v.x;
      if (i == 15) e1 = v.w;
    }
    float rsP = __shfl(rs, lane - 1, 64); rsP = (lane == 0) ? 0.f : rsP;
    float rsN = __shfl(rs, lane + 1, 64); rsN = (lane == 63) ? 0.f : rsN;
    float e0P = __shfl(e0, lane - 1, 64); e0P = (lane == 0) ? 0.f : e0P;
    float e0N = __shfl(e0, lane + 1, 64); e0N = (lane == 63) ? 0.f : e0N;
    float e1P = __shfl(e1, lane - 1, 64); e1P = (lane == 0) ? 0.f : e1P;
    float e1N = __shfl(e1, lane + 1, 64); e1N = (lane == 63) ? 0.f : e1N;
    float RS[3] = {rsP, rs, rsN};
    float E0[3] = {e0P, e0, e0N};
    float E1[3] = {e1P, e1, e1N};
    float vq = 0.f, vk = 0.f;
#pragma unroll
    for (int ky = 0; ky < 3; ky++) {
      // kx=0: RS-E1 ; kx=1: RS ; kx=2: RS-E0
      vq += (wl[0][ky * 3] + wl[0][ky * 3 + 1] + wl[0][ky * 3 + 2]) * RS[ky]
            - wl[0][ky * 3] * E1[ky] - wl[0][ky * 3 + 2] * E0[ky];
      vk += (wl[1][ky * 3] + wl[1][ky * 3 + 1] + wl[1][ky * 3 + 2]) * RS[ky]
            - wl[1][ky * 3] * E1[ky] - wl[1][ky * 3 + 2] * E0[ky];
    }
    qhm[(size_t)(b * 256 + c) * 64 + lane] = vq * (1.f / 64.f) + bl[0];
    khm[(size_t)(b * 256 + c) * 64 + lane] = vk * (1.f / 64.f) + bl[1];
  } else if (wave == 1) {
    // colsum + edge rows for col w=lane
    float cs = 0.f, f0 = 0.f, f1 = 0.f;
#pragma unroll
    for (int r = 0; r < 64; r++) {
      float v = xs[(r + 1) * 68 + 4 + lane];
      cs += v;
      if (r == 0) f0 = v;
      if (r == 63) f1 = v;
    }
    float csP = __shfl(cs, lane - 1, 64); csP = (lane == 0) ? 0.f : csP;
    float csN = __shfl(cs, lane + 1, 64); csN = (lane == 63) ? 0.f : csN;
    float f0P = __shfl(f0, lane - 1, 64); f0P = (lane == 0) ? 0.f : f0P;
    float f0N = __shfl(f0, lane + 1, 64); f0N = (lane == 63) ? 0.f : f0N;
    float f1P = __shfl(f1, lane - 1, 64); f1P = (lane == 0) ? 0.f : f1P;
    float f1N = __shfl(f1, lane + 1, 64); f1N = (lane == 63) ? 0.f : f1N;
    float CS[3] = {csP, cs, csN};
    float F0[3] = {f0P, f0, f0N};
    float F1[3] = {f1P, f1, f1N};
    float vq = 0.f, vk = 0.f;
#pragma unroll
    for (int kx = 0; kx < 3; kx++) {
      // ky=0: CS-F1 ; ky=1: CS ; ky=2: CS-F0
      vq += (wl[3][kx] + wl[3][3 + kx] + wl[3][6 + kx]) * CS[kx]
            - wl[3][kx] * F1[kx] - wl[3][6 + kx] * F0[kx];
      vk += (wl[4][kx] + wl[4][3 + kx] + wl[4][6 + kx]) * CS[kx]
            - wl[4][kx] * F1[kx] - wl[4][6 + kx] * F0[kx];
    }
    qwm[(size_t)(b * 256 + c) * 64 + lane] = vq * (1.f / 64.f) + bl[3];
    kwm[(size_t)(b * 256 + c) * 64 + lane] = vk * (1.f / 64.f) + bl[4];
  }
}

// ---------------------------------------------------------------------------
// K2: bf16 MFMA GEMM. out[m][n] = sum_k A[m][k] * W[n][k] + bias[n]
// AT==0: A is [M][256] row-major bf16 (k contiguous).
// AT==1: A is [b][k=256][m=4096] (convV layout); staged via LDS transpose.
// W: [256][256] bf16 k-contig. 128x128 tile, 4 waves, 4x4 mfma_16x16x32_bf16.
// ---------------------------------------------------------------------------
template <int OUT_BF16, int AT>
__global__ __launch_bounds__(256) void k_mm(const ushort* __restrict__ A,
                                            const ushort* __restrict__ W,
                                            const float* __restrict__ bias,
                                            void* __restrict__ out) {
  __shared__ __align__(16) ushort As[128 * 40];
  __shared__ __align__(16) ushort Bs[128 * 40];

  int m0 = blockIdx.x * 128;
  int n0 = blockIdx.y * 128;
  int tid = threadIdx.x;
  int lane = tid & 63, wave = tid >> 6;
  int wm = (wave & 1) * 64, wn = (wave >> 1) * 64;
  int tm = lane & 15, quad = lane >> 4;

  const ushort* Abase;
  if (AT) {
    Abase = A + (size_t)(m0 >> 12) * (256 * 4096) + (m0 & 4095);
  } else {
    Abase = A + (size_t)m0 * 256;
  }

  f4v acc[4][4] = {};

  for (int kc = 0; kc < 256; kc += 32) {
    __syncthreads();
    if (AT) {
      int kr2 = (tid & 15) * 2, mg = tid >> 4;
      u8v v0 = *(const u8v*)&Abase[(size_t)(kc + kr2) * 4096 + mg * 8];
      u8v v1 = *(const u8v*)&Abase[(size_t)(kc + kr2 + 1) * 4096 + mg * 8];
#pragma unroll
      for (int j = 0; j < 8; j++) {
        ushort pr[2] = {v0[j], v1[j]};
        *(uint*)&As[(mg * 8 + j) * 40 + kr2] = *(uint*)pr;
      }
#pragma unroll
      for (int h = 0; h < 2; h++) {
        int ch = tid + h * 256;
        int mr = ch >> 2, k8 = (ch & 3) * 8;
        *(float4*)&Bs[mr * 40 + k8] =
            *(const float4*)&W[(size_t)(n0 + mr) * 256 + kc + k8];
      }
    } else {
#pragma unroll
      for (int h = 0; h < 2; h++) {
        int ch = tid + h * 256;
        int mr = ch >> 2, k8 = (ch & 3) * 8;
        *(float4*)&As[mr * 40 + k8] =
            *(const float4*)&Abase[(size_t)mr * 256 + kc + k8];
        *(float4*)&Bs[mr * 40 + k8] =
            *(const float4*)&W[(size_t)(n0 + mr) * 256 + kc + k8];
      }
    }
    __syncthreads();

    s8v a[4], bfr[4];
#pragma unroll
    for (int mi = 0; mi < 4; mi++)
      a[mi] = *(const s8v*)&As[(wm + mi * 16 + tm) * 40 + quad * 8];
#pragma unroll
    for (int ni = 0; ni < 4; ni++)
      bfr[ni] = *(const s8v*)&Bs[(wn + ni * 16 + tm) * 40 + quad * 8];
#pragma unroll
    for (int mi = 0; mi < 4; mi++)
#pragma unroll
      for (int ni = 0; ni < 4; ni++)
        acc[mi][ni] = __builtin_amdgcn_mfma_f32_16x16x32_bf16(
            a[mi], bfr[ni], acc[mi][ni], 0, 0, 0);
  }

  // C/D layout: col = lane&15, row = quad*4 + reg
#pragma unroll
  for (int mi = 0; mi < 4; mi++) {
#pragma unroll
    for (int ni = 0; ni < 4; ni++) {
      int col = n0 + wn + ni * 16 + tm;
      float bv = bias[col];
#pragma unroll
      for (int r = 0; r < 4; r++) {
        int row = m0 + wm + mi * 16 + quad * 4 + r;
        float v = acc[mi][ni][r] + bv;
        if (OUT_BF16)
          ((ushort*)out)[(size_t)row * 256 + col] = f2bf(v);
        else
          ((float*)out)[(size_t)row * 256 + col] = v;
      }
    }
  }
}

// ---------------------------------------------------------------------------
// Small fp32 GEMM for pooled q/k linears, all four fused via blockIdx.z.
// ---------------------------------------------------------------------------
__global__ __launch_bounds__(256) void k_gemm4(
    const float* __restrict__ s0, const float* __restrict__ s1,
    const float* __restrict__ s2, const float* __restrict__ s3,
    const float* __restrict__ wt,
    const float* __restrict__ b0, const float* __restrict__ b1,
    const float* __restrict__ b2, const float* __restrict__ b3,
    float* __restrict__ d0, float* __restrict__ d1,
    float* __restrict__ d2, float* __restrict__ d3) {
  __shared__ __align__(16) float As[32 * 64];
  __shared__ __align__(16) float Ws[32 * 64];

  int z = blockIdx.z;
  const float* At = z == 0 ? s0 : z == 1 ? s1 : z == 2 ? s2 : s3;
  const float* Wt = wt + (size_t)z * 65536;
  const float* bias = z == 0 ? b0 : z == 1 ? b1 : z == 2 ? b2 : b3;
  float* Cout = z == 0 ? d0 : z == 1 ? d1 : z == 2 ? d2 : d3;

  int m0 = blockIdx.x * 64;
  int n0 = blockIdx.y * 64;
  int tid = threadIdx.x;
  const float* Ab = At + (size_t)(m0 >> 6) * 256 * 64;

  int tx = tid & 15, ty = tid >> 4;
  int lk = tid >> 6;
  int lm = tid & 63;
  float acc[4][4] = {};

  for (int kc = 0; kc < 256; kc += 32) {
    __syncthreads();
#pragma unroll
    for (int r = 0; r < 8; r++) {
      int kk = lk + r * 4;
      As[kk * 64 + lm] = Ab[(size_t)(kc + kk) * 64 + lm];
      Ws[kk * 64 + lm] = Wt[(kc + kk) * 256 + n0 + lm];
    }
    __syncthreads();
#pragma unroll
    for (int kk = 0; kk < 32; kk++) {
      float4 av = *(const float4*)&As[kk * 64 + ty * 4];
      float4 wv = *(const float4*)&Ws[kk * 64 + tx * 4];
      float a_[4] = {av.x, av.y, av.z, av.w};
      float w_[4] = {wv.x, wv.y, wv.z, wv.w};
#pragma unroll
      for (int ii = 0; ii < 4; ii++)
#pragma unroll
        for (int jj = 0; jj < 4; jj++) acc[ii][jj] += a_[ii] * w_[jj];
    }
  }

#pragma unroll
  for (int ii = 0; ii < 4; ii++) {
    int m = m0 + ty * 4 + ii;
#pragma unroll
    for (int jj = 0; jj < 4; jj++) {
      int n = n0 + tx * 4 + jj;
      Cout[(size_t)m * 256 + n] = acc[ii][jj] + bias[n];
    }
  }
}

// ---------------------------------------------------------------------------
// K3: attention softmax, both axes fused. 256 threads = 4 rows per block.
// ---------------------------------------------------------------------------
__global__ __launch_bounds__(256) void k_attn(
    const float* __restrict__ qh, const float* __restrict__ kh,
    const float* __restrict__ Bh, float* __restrict__ ah,
    const float* __restrict__ qw, const float* __restrict__ kw,
    const float* __restrict__ Bw, float* __restrict__ aw, float scale) {
  __shared__ float qs[4][32];
  __shared__ float ks[64 * 33];

  int bx = blockIdx.x;
  int setw = bx >> 11;
  int rem = bx & 2047;
  int ig = rem & 15, hd = (rem >> 4) & 7, b = rem >> 7;
  int tid = threadIdx.x;
  int wave = tid >> 6, lane = tid & 63;
  int i = ig * 4 + wave;

  const float* q = setw ? qw : qh;
  const float* k = setw ? kw : kh;
  const float* Bb = setw ? Bw : Bh;
  float* attn = setw ? aw : ah;

  if (lane < 32) qs[wave][lane] = q[(size_t)(b * 64 + i) * 256 + hd * 32 + lane];
#pragma unroll
  for (int it = 0; it < 8; it++) {
    int f = tid + it * 256;
    int j = f >> 5, d = f & 31;
    ks[j * 33 + d] = k[(size_t)(b * 64 + j) * 256 + hd * 32 + d];
  }
  __syncthreads();

  int j = lane;
  float dot = 0.f;
#pragma unroll
  for (int d = 0; d < 32; d++) dot += qs[wave][d] * ks[j * 33 + d];
  float logit = dot * scale + Bb[(hd * 64 + i) * 64 + j];
  float mx = logit;
#pragma unroll
  for (int off = 32; off > 0; off >>= 1)
    mx = fmaxf(mx, __shfl_xor(mx, off, 64));
  float e = __expf(logit - mx);
  float sum = e;
#pragma unroll
  for (int off = 32; off > 0; off >>= 1) sum += __shfl_xor(sum, off, 64);
  attn[(size_t)((b * 8 + hd) * 64 + i) * 64 + j] = e / sum;
}

// ---------------------------------------------------------------------------
// K5a: r1[b][hd][h][w*32+dv] = sum_j attn_h[.,h,j] * vlin[(b,j,w)][hd*32+dv]
// ---------------------------------------------------------------------------
__global__ __launch_bounds__(256) void k_av(const float* __restrict__ attn,
                                            const ushort* __restrict__ vlin,
                                            ushort* __restrict__ r1) {
  __shared__ __align__(16) float As[64 * 65];
  __shared__ __align__(16) float Bs[64 * 64];

  int bx = blockIdx.x;
  int cc = bx & 31, hd = (bx >> 5) & 7, b = bx >> 8;
  int tid = threadIdx.x;
  int l = tid & 63, g = tid >> 6;

  const float* ap = attn + (size_t)(b * 8 + hd) * 4096;
#pragma unroll
  for (int r = 0; r < 16; r++) {
    int i = g + r * 4;
    As[l * 65 + i] = ap[i * 64 + l];
  }
  int colg0 = cc * 64;
#pragma unroll
  for (int r = 0; r < 8; r++) {
    int f = tid + r * 256;                 // 0..2047
    int j = f >> 5, p2 = f & 31;
    int colg = colg0 + p2 * 2;
    int w = colg >> 5, dv = colg & 31;     // dv even
    uint u = *(const uint*)&vlin[(size_t)(b * 4096 + j * 64 + w) * 256 +
                                 hd * 32 + dv];
    Bs[j * 64 + p2 * 2] = bf2f((ushort)(u & 0xffff));
    Bs[j * 64 + p2 * 2 + 1] = bf2f((ushort)(u >> 16));
  }
  __syncthreads();

  int tx = tid & 15, ty = tid >> 4;
  float acc[4][4] = {};
  for (int j = 0; j < 64; j++) {
    float4 bv = *(const float4*)&Bs[j * 64 + tx * 4];
    float b_[4] = {bv.x, bv.y, bv.z, bv.w};
    float a_[4];
#pragma unroll
    for (int ii = 0; ii < 4; ii++) a_[ii] = As[j * 65 + ty * 4 + ii];
#pragma unroll
    for (int ii = 0; ii < 4; ii++)
#pragma unroll
      for (int jj = 0; jj < 4; jj++) acc[ii][jj] += a_[ii] * b_[jj];
  }

  ushort* rp = r1 + (size_t)(b * 8 + hd) * 64 * 2048;
#pragma unroll
  for (int ii = 0; ii < 4; ii++) {
    int row = ty * 4 + ii;
    ushort pk[4];
#pragma unroll
    for (int jj = 0; jj < 4; jj++) pk[jj] = f2bf(acc[ii][jj]);
    *(uint2*)&rp[(size_t)row * 2048 + colg0 + tx * 4] = *(uint2*)pk;
  }
}

// ---------------------------------------------------------------------------
// K5b: yT[(b*4096+h*64+w')][hd*32+dv] = sum_w r1[b,hd,h,w*32+dv]*attnw[w][w']
// ---------------------------------------------------------------------------
__global__ __launch_bounds__(256) void k_rw(const ushort* __restrict__ r1,
                                            const float* __restrict__ attnw,
                                            ushort* __restrict__ yT) {
  __shared__ __align__(16) float rr[2048];
  __shared__ __align__(16) float aw[4096];

  int bx = blockIdx.x;
  int h = bx & 63, hd = (bx >> 6) & 7, b = bx >> 9;
  int tid = threadIdx.x;

  const uint* rp = (const uint*)(r1 + (size_t)((b * 8 + hd) * 64 + h) * 2048);
#pragma unroll
  for (int r = 0; r < 4; r++) {
    uint u = rp[tid + r * 256];
    rr[2 * (tid + r * 256)] = bf2f((ushort)(u & 0xffff));
    rr[2 * (tid + r * 256) + 1] = bf2f((ushort)(u >> 16));
  }
  const float* ap = attnw + (size_t)(b * 8 + hd) * 4096;
#pragma unroll
  for (int r = 0; r < 4; r++)
    *(float4*)&aw[4 * (tid + r * 256)] = *(const float4*)&ap[4 * (tid + r * 256)];
  __syncthreads();

  int wp = tid & 63;
  int dv0 = (tid >> 6) * 8;
  float acc[8] = {};
  for (int w = 0; w < 64; w++) {
    float a = aw[w * 64 + wp];
    float4 r4a = *(const float4*)&rr[w * 32 + dv0];
    float4 r4b = *(const float4*)&rr[w * 32 + dv0 + 4];
    float rv[8] = {r4a.x, r4a.y, r4a.z, r4a.w, r4b.x, r4b.y, r4b.z, r4b.w};
#pragma unroll
    for (int d = 0; d < 8; d++) acc[d] += a * rv[d];
  }

  ushort* yp = yT + (size_t)(b * 4096 + h * 64 + wp) * 256 + hd * 32 + dv0;
  ushort pk[8];
#pragma unroll
  for (int d = 0; d < 8; d++) pk[d] = f2bf(acc[d]);
  *(uint4*)yp = *(uint4*)pk;
}

// ---------------------------------------------------------------------------
extern "C" void kernel_launch(void* const* d_in, const int* in_sizes, int n_in,
                              void* d_out, int out_size, void* d_ws,
                              size_t ws_size, hipStream_t stream) {
  const float* x      = (const float*)d_in[0];
  const float* dwqh_w = (const float*)d_in[1];
  const float* dwqh_b = (const float*)d_in[2];
  const float* fcqh_w = (const float*)d_in[3];
  const float* fcqh_b = (const float*)d_in[4];
  const float* dwkh_w = (const float*)d_in[5];
  const float* dwkh_b = (const float*)d_in[6];
  const float* fckh_w = (const float*)d_in[7];
  const float* fckh_b = (const float*)d_in[8];
  const float* Bh     = (const float*)d_in[9];
  const float* dwv_w  = (const float*)d_in[10];
  const float* dwv_b  = (const float*)d_in[11];
  const float* fcv_w  = (const float*)d_in[12];
  const float* fcv_b  = (const float*)d_in[13];
  const float* dwqw_w = (const float*)d_in[14];
  const float* dwqw_b = (const float*)d_in[15];
  const float* fcqw_w = (const float*)d_in[16];
  const float* fcqw_b = (const float*)d_in[17];
  const float* dwkw_w = (const float*)d_in[18];
  const float* dwkw_b = (const float*)d_in[19];
  const float* fckw_w = (const float*)d_in[20];
  const float* fckw_b = (const float*)d_in[21];
  const float* Bw     = (const float*)d_in[22];
  const float* fco_w  = (const float*)d_in[23];
  const float* fco_b  = (const float*)d_in[24];

  char* base = (char*)d_ws;
  ushort* P1 = (ushort*)(base);                  // convV, later r1
  ushort* P2 = (ushort*)(base + 33554432);       // yT
  ushort* P3 = (ushort*)(base + 67108864);       // vlin
  float*  wt   = (float*)(base + 100663296);     // 4 x 65536 fp32
  ushort* wv_bf = (ushort*)(base + 101711872);   // 2 x 65536 bf16
  float* qhm = (float*)(base + 101974016);
  float* khm = qhm + 262144;
  float* qwm = khm + 262144;
  float* kwm = qwm + 262144;
  float* qhl = kwm + 262144;
  float* khl = qhl + 262144;
  float* qwl = khl + 262144;
  float* kwl = qwl + 262144;
  float* ah  = kwl + 262144;                     // 524288
  float* awt = ah + 524288;                      // 524288
  if (ws_size < 115000000ull) return;

  const float scale = 0.17677669529663687f;  // 32^-0.5

  k_prep<<<1536, 256, 0, stream>>>(fcqh_w, fckh_w, fcqw_w, fckw_w, fcv_w,
                                   fco_w, wt, wv_bf);
  k_conv<<<4096, 256, 0, stream>>>(x, dwqh_w, dwqh_b, dwkh_w, dwkh_b, dwv_w,
                                   dwv_b, dwqw_w, dwqw_b, dwkw_w, dwkw_b, P1,
                                   qhm, khm, qwm, kwm);
  k_gemm4<<<dim3(16, 4, 4), 256, 0, stream>>>(qhm, khm, qwm, kwm, wt, fcqh_b,
                                              fckh_b, fcqw_b, fckw_b, qhl, khl,
                                              qwl, kwl);
  k_attn<<<4096, 256, 0, stream>>>(qhl, khl, Bh, ah, qwl, kwl, Bw, awt, scale);
  k_mm<1, 1><<<dim3(512, 2), 256, 0, stream>>>(P1, wv_bf, fcv_b, P3);
  k_av<<<4096, 256, 0, stream>>>(ah, P3, P1);
  k_rw<<<8192, 256, 0, stream>>>(P1, awt, P2);
  k_mm<0, 0><<<dim3(512, 2), 256, 0, stream>>>(P2, wv_bf + 65536, fco_b, d_out);
}